// Round 5
// baseline (165.337 us; speedup 1.0000x reference)
//
#include <hip/hip_runtime.h>
#include <stdint.h>

typedef __attribute__((ext_vector_type(8))) short short8;
typedef __attribute__((ext_vector_type(4))) float f32x4;
typedef __attribute__((ext_vector_type(4))) unsigned short ushort4v;
typedef __attribute__((ext_vector_type(2))) unsigned int uint2v;

static __device__ __forceinline__ unsigned short f2b(float f) {
  union { float f; unsigned int u; } v; v.f = f;
  unsigned int r = v.u + 0x7FFFu + ((v.u >> 16) & 1u);
  return (unsigned short)(r >> 16);
}

static __device__ __forceinline__ float exp2fast(float x) {
#if __has_builtin(__builtin_amdgcn_exp2f)
  return __builtin_amdgcn_exp2f(x);
#else
  return exp2f(x);
#endif
}

static __device__ __forceinline__ unsigned int cvtpk(float lo, float hi) {
  unsigned int r;
  asm("v_cvt_pk_bf16_f32 %0, %1, %2" : "=v"(r) : "v"(lo), "v"(hi));
  return r;
}

// Cross-lane ^16 / ^32 reduce via permlane*_swap (VALU) with ds-shfl fallback.
static __device__ __forceinline__ float xor16max(float x) {
#if __has_builtin(__builtin_amdgcn_permlane16_swap)
  unsigned u = __float_as_uint(x);
  uint2v r = __builtin_amdgcn_permlane16_swap(u, u, false, false);
  return fmaxf(__uint_as_float(r[0]), __uint_as_float(r[1]));
#else
  return fmaxf(x, __shfl_xor(x, 16));
#endif
}
static __device__ __forceinline__ float xor32max(float x) {
#if __has_builtin(__builtin_amdgcn_permlane32_swap)
  unsigned u = __float_as_uint(x);
  uint2v r = __builtin_amdgcn_permlane32_swap(u, u, false, false);
  return fmaxf(__uint_as_float(r[0]), __uint_as_float(r[1]));
#else
  return fmaxf(x, __shfl_xor(x, 32));
#endif
}
static __device__ __forceinline__ float xor16add(float x) {
#if __has_builtin(__builtin_amdgcn_permlane16_swap)
  unsigned u = __float_as_uint(x);
  uint2v r = __builtin_amdgcn_permlane16_swap(u, u, false, false);
  return __uint_as_float(r[0]) + __uint_as_float(r[1]);
#else
  return x + __shfl_xor(x, 16);
#endif
}
static __device__ __forceinline__ float xor32add(float x) {
#if __has_builtin(__builtin_amdgcn_permlane32_swap)
  unsigned u = __float_as_uint(x);
  uint2v r = __builtin_amdgcn_permlane32_swap(u, u, false, false);
  return __uint_as_float(r[0]) + __uint_as_float(r[1]);
#else
  return x + __shfl_xor(x, 32);
#endif
}

static __device__ __forceinline__ void gload16(const void* g, void* l) {
  __builtin_amdgcn_global_load_lds(
      (const __attribute__((address_space(1))) unsigned int*)g,
      (__attribute__((address_space(3))) unsigned int*)l, 16, 0, 0);
}

// ---------------- prep kernels ----------------

__global__ __launch_bounds__(256) void cast_x_kernel(const float* __restrict__ x,
                                                     unsigned short* __restrict__ xb) {
  int i = (blockIdx.x * 256 + threadIdx.x) * 4;
  float4 v = *(const float4*)(x + i);
  ushort4v o = { f2b(v.x), f2b(v.y), f2b(v.z), f2b(v.w) };
  *(ushort4v*)(xb + i) = o;
}

__global__ __launch_bounds__(256) void transpose_cast_kernel(
    const float* __restrict__ wq, const float* __restrict__ wk,
    const float* __restrict__ wv, const float* __restrict__ wo,
    unsigned short* __restrict__ wT) {
  const int z = blockIdx.z;
  const float* src = (z == 0) ? wq : (z == 1) ? wk : (z == 2) ? wv : wo;
  unsigned short* dst = wT + (size_t)z * 1048576;
  __shared__ float t[32][33];
  const int tid = threadIdx.x;
  const int tx = tid & 31, ty = tid >> 5;
  const int n0 = blockIdx.x * 32, k0 = blockIdx.y * 32;
#pragma unroll
  for (int i = 0; i < 4; ++i) {
    int r = ty + i * 8;
    t[r][tx] = src[(size_t)(k0 + r) * 1024 + n0 + tx];
  }
  __syncthreads();
#pragma unroll
  for (int i = 0; i < 4; ++i) {
    int r = ty + i * 8;
    dst[(size_t)(n0 + r) * 1024 + k0 + tx] = f2b(t[tx][r]);
  }
}

__global__ __launch_bounds__(256) void rope_tab_kernel(float* __restrict__ ct,
                                                       float* __restrict__ st) {
  int i = blockIdx.x * 256 + threadIdx.x;  // 2048*32 entries
  int s = i >> 5, p = i & 31;
  float ang = (float)s * powf(10000.0f, -(float)(2 * p) / 64.0f);
  ct[i] = cosf(ang);
  st[i] = sinf(ang);
}

// ---------------- GEMM (A: MxK row-major bf16, Bt: NxK row-major bf16) ----------------
// mode 0: Q epilogue (RoPE + fold 0.125*log2e, write (h,b,s,d)); mode 1: K epilogue;
// mode 2: V epilogue (write transposed (h,b,d,s)); mode 3: fp32 row-major out.

__global__ __launch_bounds__(256) void gemm_kernel(
    const unsigned short* __restrict__ A, const unsigned short* __restrict__ WT,
    unsigned short* __restrict__ Qb, unsigned short* __restrict__ Kb,
    unsigned short* __restrict__ VTb, float* __restrict__ Fout,
    const float* __restrict__ ctab, const float* __restrict__ stab, int finalMode) {
  __shared__ unsigned short As[128 * 32];
  __shared__ unsigned short Bs[128 * 32];
  const int tid = threadIdx.x;
  const int w = tid >> 6, lane = tid & 63;
  const int m0 = blockIdx.x * 128, n0 = blockIdx.y * 128;
  int mode;
  const unsigned short* Bt;
  if (finalMode) { mode = 3; Bt = WT; }
  else { mode = blockIdx.z; Bt = WT + (size_t)mode * 1048576; }
  const int wr = w >> 1, wc = w & 1;
  const int srow = lane >> 2, scol = lane & 3;
  f32x4 acc[4][4] = {};
  for (int k0 = 0; k0 < 1024; k0 += 32) {
#pragma unroll
    for (int c = 0; c < 2; ++c) {
      int chunk = w * 2 + c;
      gload16(A + (size_t)(m0 + chunk * 16 + srow) * 1024 + k0 + scol * 8,
              (char*)As + chunk * 1024);
      gload16(Bt + (size_t)(n0 + chunk * 16 + srow) * 1024 + k0 + scol * 8,
              (char*)Bs + chunk * 1024);
    }
    __syncthreads();
    short8 af[4], bf[4];
#pragma unroll
    for (int i = 0; i < 4; ++i) {
      af[i] = *(const short8*)((const char*)As +
              ((wr * 64 + i * 16 + (lane & 15)) * 64 + (lane >> 4) * 16));
      bf[i] = *(const short8*)((const char*)Bs +
              ((wc * 64 + i * 16 + (lane & 15)) * 64 + (lane >> 4) * 16));
    }
#pragma unroll
    for (int i = 0; i < 4; ++i)
#pragma unroll
      for (int j = 0; j < 4; ++j)
        acc[i][j] = __builtin_amdgcn_mfma_f32_16x16x32_bf16(af[i], bf[j], acc[i][j], 0, 0, 0);
    __syncthreads();
  }

  if (mode < 2) {
    unsigned short* dst = mode ? Kb : Qb;
    const float qscale = mode ? 1.0f : 0.125f * 1.44269504088896f;
#pragma unroll
    for (int i = 0; i < 4; ++i) {
#pragma unroll
      for (int j = 0; j < 4; ++j) {
        int n = n0 + wc * 64 + j * 16 + (lane & 15);
        int h = n >> 6, d = n & 63;
        int pairIdx = d >> 1;
        bool even = (n & 1) == 0;
#pragma unroll
        for (int r = 0; r < 4; ++r) {
          int m = m0 + wr * 64 + i * 16 + (lane >> 4) * 4 + r;
          int b = m >> 11, s = m & 2047;
          float v = acc[i][j][r];
          float pv = __shfl_xor(v, 1);
          float c = ctab[s * 32 + pairIdx], sn = stab[s * 32 + pairIdx];
          float ov = (even ? (v * c - pv * sn) : (pv * sn + v * c)) * qscale;
          dst[(size_t)((h * 2 + b) * 2048 + s) * 64 + d] = f2b(ov);
        }
      }
    }
  } else if (mode == 2) {
#pragma unroll
    for (int i = 0; i < 4; ++i) {
#pragma unroll
      for (int j = 0; j < 4; ++j) {
        int n = n0 + wc * 64 + j * 16 + (lane & 15);
        int h = n >> 6, d = n & 63;
        int mBase = m0 + wr * 64 + i * 16 + (lane >> 4) * 4;
        int b = mBase >> 11, s = mBase & 2047;
        ushort4v pk = { f2b(acc[i][j][0]), f2b(acc[i][j][1]),
                        f2b(acc[i][j][2]), f2b(acc[i][j][3]) };
        *(ushort4v*)(VTb + (size_t)((h * 2 + b) * 64 + d) * 2048 + s) = pk;
      }
    }
  } else {
#pragma unroll
    for (int i = 0; i < 4; ++i)
#pragma unroll
      for (int j = 0; j < 4; ++j) {
        int n = n0 + wc * 64 + j * 16 + (lane & 15);
#pragma unroll
        for (int r = 0; r < 4; ++r) {
          int m = m0 + wr * 64 + i * 16 + (lane >> 4) * 4 + r;
          Fout[(size_t)m * 1024 + n] = acc[i][j][r];
        }
      }
  }
}

// ---------------- causal flash attention ----------------
// Pair-balanced blocks (qtL=bx, qtH=31-bx). Swapped-QK: S^T = mfma(K,Q); lane
// owns q=lane&15, k-rows 16ct+4lh+r. Fused H+L per iteration: shared K/V frag
// reads, two interleaved softmax chains (2x ILP on the latency chain).
// Cross-lane reduces via permlane swaps (VALU). l-sum reduce deferred to
// epilogue. K/V double-buffered: 1 syncthreads per k-tile.

__device__ __forceinline__ short8 ldfrag(const unsigned short* base_, int ct, int half,
                                         int lq, int lh) {
  const int swq = (lq & 7) << 4;
  return *(const short8*)((const char*)base_ + (ct * 16 + lq) * 128 +
                          ((half * 64 + lh * 16) ^ swq));
}

__device__ __forceinline__ void qk8(f32x4* s, const short8* kf, const short8* aq) {
#pragma unroll
  for (int ct = 0; ct < 4; ++ct) {
    s[ct] = __builtin_amdgcn_mfma_f32_16x16x32_bf16(kf[ct * 2], aq[0], s[ct], 0, 0, 0);
    s[ct] = __builtin_amdgcn_mfma_f32_16x16x32_bf16(kf[ct * 2 + 1], aq[1], s[ct], 0, 0, 0);
  }
}

__device__ __forceinline__ void cmask(f32x4* s, int rel) {
#pragma unroll
  for (int ct = 0; ct < 4; ++ct)
#pragma unroll
    for (int r = 0; r < 4; ++r)
      if (ct * 16 + r > rel) s[ct][r] = -__builtin_inff();
}

__device__ __forceinline__ void softmax_path(f32x4* s, float& m, float& ls, f32x4* o) {
  float mx0 = fmaxf(fmaxf(s[0][0], s[0][1]), fmaxf(s[0][2], s[0][3]));
  float mx1 = fmaxf(fmaxf(s[1][0], s[1][1]), fmaxf(s[1][2], s[1][3]));
  float mx2 = fmaxf(fmaxf(s[2][0], s[2][1]), fmaxf(s[2][2], s[2][3]));
  float mx3 = fmaxf(fmaxf(s[3][0], s[3][1]), fmaxf(s[3][2], s[3][3]));
  float mx = fmaxf(fmaxf(mx0, mx1), fmaxf(mx2, mx3));
  mx = xor16max(mx);
  mx = xor32max(mx);
  float nm = fmaxf(m, mx);
  float al = exp2fast(m - nm);
  m = nm;
  float ps = 0.f;
#pragma unroll
  for (int ct = 0; ct < 4; ++ct)
#pragma unroll
    for (int r = 0; r < 4; ++r) {
      float p = exp2fast(s[ct][r] - nm);
      s[ct][r] = p;
      ps += p;
    }
  ls = ls * al + ps;  // per-lane partial; cross-lane reduce deferred to epilogue
#pragma unroll
  for (int ct = 0; ct < 4; ++ct)
#pragma unroll
    for (int r = 0; r < 4; ++r) o[ct][r] *= al;
}

__device__ __forceinline__ void pwrite(const f32x4* s, char* Psw, int lq, int lh) {
  const int swq = (lq & 7) << 4;
#pragma unroll
  for (int ct = 0; ct < 4; ++ct) {
    uint2v pk = { cvtpk(s[ct][0], s[ct][1]), cvtpk(s[ct][2], s[ct][3]) };
    *(uint2v*)(Psw + lq * 128 + ((ct * 32 + lh * 8) ^ swq)) = pk;
  }
}

__device__ __forceinline__ void pread(short8* pa, const char* Psw, int lq, int lh) {
  const int swq = (lq & 7) << 4;
#pragma unroll
  for (int half = 0; half < 2; ++half)
    pa[half] = *(const short8*)(Psw + lq * 128 + ((half * 64 + lh * 16) ^ swq));
}

__device__ __forceinline__ void store_path(
    const f32x4* o, float ls, char* Psw, unsigned short* __restrict__ Ob,
    int lq, int lh, int qrow_base, int h, int b) {
  float l = xor32add(xor16add(ls));
  float invl = 1.0f / l;
  const int swq = (lq & 7) << 4;
#pragma unroll
  for (int ct = 0; ct < 4; ++ct)
#pragma unroll
    for (int r = 0; r < 4; ++r) {
      int d = ct * 16 + lh * 4 + r;
      *(unsigned short*)(Psw + lq * 128 + ((2 * d) ^ swq)) = f2b(o[ct][r] * invl);
    }
}

__global__ __launch_bounds__(256) void attn_kernel(
    const unsigned short* __restrict__ Qb, const unsigned short* __restrict__ Kb,
    const unsigned short* __restrict__ VTb, unsigned short* __restrict__ Ob) {
  __shared__ unsigned short Ks[2][64 * 64];
  __shared__ unsigned short Vs[2][64 * 64];
  __shared__ unsigned short Ps[2][4 * 16 * 64];  // [path][wave regions]
  const int tid = threadIdx.x, w = tid >> 6, lane = tid & 63;
  const int qtL = blockIdx.x, qtH = 31 - blockIdx.x;
  const int hb = blockIdx.y;
  const int h = hb >> 1, b = hb & 1;
  const unsigned short* Qhb = Qb + (size_t)hb * 2048 * 64;
  const unsigned short* Khb = Kb + (size_t)hb * 2048 * 64;
  const unsigned short* Vhb = VTb + (size_t)hb * 64 * 2048;
  char* PsH = (char*)Ps[0] + w * 2048;
  char* PsL = (char*)Ps[1] + w * 2048;
  const int lq = lane & 15, lh = lane >> 4;
  const int wq16 = w * 16;
  const int rel = wq16 + lq - 4 * lh;  // diag-mask threshold (tile-local)

  short8 aqL[2], aqH[2];
  {
    int rowL = qtL * 64 + wq16 + lq;
    int rowH = qtH * 64 + wq16 + lq;
#pragma unroll
    for (int half = 0; half < 2; ++half) {
      aqL[half] = *(const short8*)(Qhb + (size_t)rowL * 64 + half * 32 + lh * 8);
      aqH[half] = *(const short8*)(Qhb + (size_t)rowH * 64 + half * 32 + lh * 8);
    }
  }
  float mL = -__builtin_inff(), lsL = 0.f;
  float mH = -__builtin_inff(), lsH = 0.f;
  f32x4 oL[4] = {}, oH[4] = {};

  // staging: thread owns rows r0, r0+32 (16B each)
  const int r0 = tid >> 3, f0 = tid & 7;
  const int so0 = r0 * 128 + ((f0 * 16) ^ ((r0 & 7) << 4));
  short8 gK[2], gV[2];
  gK[0] = *(const short8*)(Khb + (size_t)r0 * 64 + f0 * 8);
  gK[1] = *(const short8*)(Khb + (size_t)(r0 + 32) * 64 + f0 * 8);
  gV[0] = *(const short8*)(Vhb + (size_t)r0 * 2048 + f0 * 8);
  gV[1] = *(const short8*)(Vhb + (size_t)(r0 + 32) * 2048 + f0 * 8);
  *(short8*)((char*)Ks[0] + so0) = gK[0];
  *(short8*)((char*)Ks[0] + so0 + 32 * 128) = gK[1];
  *(short8*)((char*)Vs[0] + so0) = gV[0];
  *(short8*)((char*)Vs[0] + so0 + 32 * 128) = gV[1];
  __syncthreads();

  for (int kt = 0; kt <= qtH; ++kt) {
    const int cur = kt & 1;
    if (kt < qtH) {  // issue next tile's loads; latency hides under compute
      int kk0 = (kt + 1) * 64;
      gK[0] = *(const short8*)(Khb + (size_t)(kk0 + r0) * 64 + f0 * 8);
      gK[1] = *(const short8*)(Khb + (size_t)(kk0 + r0 + 32) * 64 + f0 * 8);
      gV[0] = *(const short8*)(Vhb + (size_t)r0 * 2048 + kk0 + f0 * 8);
      gV[1] = *(const short8*)(Vhb + (size_t)(r0 + 32) * 2048 + kk0 + f0 * 8);
    }
    if (kt <= qtL) {
      // ---- fused H+L: shared K/V frags, two interleaved softmax chains ----
      short8 kf[8];
#pragma unroll
      for (int ct = 0; ct < 4; ++ct) {
        kf[ct * 2] = ldfrag(Ks[cur], ct, 0, lq, lh);
        kf[ct * 2 + 1] = ldfrag(Ks[cur], ct, 1, lq, lh);
      }
      f32x4 sH[4] = {}, sL[4] = {};
      __builtin_amdgcn_s_setprio(1);
      qk8(sH, kf, aqH);
      qk8(sL, kf, aqL);
      __builtin_amdgcn_s_setprio(0);
      if (kt == qtL) cmask(sL, rel);
      softmax_path(sH, mH, lsH, oH);
      softmax_path(sL, mL, lsL, oL);
      pwrite(sH, PsH, lq, lh);
      pwrite(sL, PsL, lq, lh);
      __builtin_amdgcn_wave_barrier();
      short8 paH[2], paL[2];
      pread(paH, PsH, lq, lh);
      pread(paL, PsL, lq, lh);
      __builtin_amdgcn_s_setprio(1);
#pragma unroll
      for (int ct = 0; ct < 4; ++ct) {
        short8 v0 = ldfrag(Vs[cur], ct, 0, lq, lh);
        short8 v1 = ldfrag(Vs[cur], ct, 1, lq, lh);
        oH[ct] = __builtin_amdgcn_mfma_f32_16x16x32_bf16(v0, paH[0], oH[ct], 0, 0, 0);
        oH[ct] = __builtin_amdgcn_mfma_f32_16x16x32_bf16(v1, paH[1], oH[ct], 0, 0, 0);
        oL[ct] = __builtin_amdgcn_mfma_f32_16x16x32_bf16(v0, paL[0], oL[ct], 0, 0, 0);
        oL[ct] = __builtin_amdgcn_mfma_f32_16x16x32_bf16(v1, paL[1], oL[ct], 0, 0, 0);
      }
      __builtin_amdgcn_s_setprio(0);
    } else {
      // ---- H only ----
      short8 kf[8];
#pragma unroll
      for (int ct = 0; ct < 4; ++ct) {
        kf[ct * 2] = ldfrag(Ks[cur], ct, 0, lq, lh);
        kf[ct * 2 + 1] = ldfrag(Ks[cur], ct, 1, lq, lh);
      }
      f32x4 sH[4] = {};
      __builtin_amdgcn_s_setprio(1);
      qk8(sH, kf, aqH);
      __builtin_amdgcn_s_setprio(0);
      if (kt == qtH) cmask(sH, rel);
      softmax_path(sH, mH, lsH, oH);
      pwrite(sH, PsH, lq, lh);
      __builtin_amdgcn_wave_barrier();
      short8 paH[2];
      pread(paH, PsH, lq, lh);
      __builtin_amdgcn_s_setprio(1);
#pragma unroll
      for (int ct = 0; ct < 4; ++ct) {
        short8 v0 = ldfrag(Vs[cur], ct, 0, lq, lh);
        short8 v1 = ldfrag(Vs[cur], ct, 1, lq, lh);
        oH[ct] = __builtin_amdgcn_mfma_f32_16x16x32_bf16(v0, paH[0], oH[ct], 0, 0, 0);
        oH[ct] = __builtin_amdgcn_mfma_f32_16x16x32_bf16(v1, paH[1], oH[ct], 0, 0, 0);
      }
      __builtin_amdgcn_s_setprio(0);
    }
    if (kt < qtH) {  // write next tile into the other buffer
      *(short8*)((char*)Ks[cur ^ 1] + so0) = gK[0];
      *(short8*)((char*)Ks[cur ^ 1] + so0 + 32 * 128) = gK[1];
      *(short8*)((char*)Vs[cur ^ 1] + so0) = gV[0];
      *(short8*)((char*)Vs[cur ^ 1] + so0 + 32 * 128) = gV[1];
    }
    __syncthreads();
  }

  // epilogue: O^T -> per-wave LDS regions -> coalesced stores (both paths, 1 barrier)
  store_path(oH, lsH, PsH, Ob, lq, lh, qtH * 64 + wq16, h, b);
  store_path(oL, lsL, PsL, Ob, lq, lh, qtL * 64 + wq16, h, b);
  __builtin_amdgcn_wave_barrier();
#pragma unroll
  for (int pass = 0; pass < 2; ++pass) {
    int q2 = pass * 8 + (lane >> 3), d0 = (lane & 7) * 8;
    int swq2 = (q2 & 7) << 4;
    short8 vH = *(const short8*)(PsH + q2 * 128 + ((2 * d0) ^ swq2));
    short8 vL = *(const short8*)(PsL + q2 * 128 + ((2 * d0) ^ swq2));
    int sH_ = qtH * 64 + wq16 + q2;
    int sL_ = qtL * 64 + wq16 + q2;
    *(short8*)(Ob + ((size_t)(b * 2048 + sH_)) * 1024 + h * 64 + d0) = vH;
    *(short8*)(Ob + ((size_t)(b * 2048 + sL_)) * 1024 + h * 64 + d0) = vL;
  }
}

// ---------------- launch ----------------

extern "C" void kernel_launch(void* const* d_in, const int* in_sizes, int n_in,
                              void* d_out, int out_size, void* d_ws, size_t ws_size,
                              hipStream_t stream) {
  const float* x  = (const float*)d_in[0];
  const float* wq = (const float*)d_in[1];
  const float* wk = (const float*)d_in[2];
  const float* wv = (const float*)d_in[3];
  const float* wo = (const float*)d_in[4];
  float* out = (float*)d_out;

  char* ws = (char*)d_ws;
  const size_t SZ = 8388608;  // 8 MiB
  unsigned short* xb  = (unsigned short*)(ws);
  unsigned short* wT  = (unsigned short*)(ws + SZ);       // 4 x 2MiB (q,k,v,o)
  unsigned short* Qb  = (unsigned short*)(ws + 2 * SZ);
  unsigned short* Kb  = (unsigned short*)(ws + 3 * SZ);
  unsigned short* VTb = (unsigned short*)(ws + 4 * SZ);
  unsigned short* Ob  = (unsigned short*)(ws + 5 * SZ);
  float* ctab = (float*)(ws + 6 * SZ);
  float* stab = (float*)(ws + 6 * SZ + 262144);
  if (ws_size < 6 * SZ + 2 * 262144) return;  // ws too small: fail loudly (zeros)

  cast_x_kernel<<<4096, 256, 0, stream>>>(x, xb);
  transpose_cast_kernel<<<dim3(32, 32, 4), 256, 0, stream>>>(wq, wk, wv, wo, wT);
  rope_tab_kernel<<<256, 256, 0, stream>>>(ctab, stab);
  gemm_kernel<<<dim3(32, 8, 3), 256, 0, stream>>>(xb, wT, Qb, Kb, VTb, nullptr, ctab, stab, 0);
  attn_kernel<<<dim3(16, 32), 256, 0, stream>>>(Qb, Kb, VTb, Ob);
  gemm_kernel<<<dim3(32, 8, 1), 256, 0, stream>>>(Ob, wT + 3 * 1048576, Qb, Kb, VTb, out,
                                                  ctab, stab, 1);
}

// Round 6
// 133.911 us; speedup vs baseline: 1.2347x; 1.2347x over previous
//
#include <hip/hip_runtime.h>
#include <stdint.h>

typedef __attribute__((ext_vector_type(8))) short short8;
typedef __attribute__((ext_vector_type(4))) float f32x4;
typedef __attribute__((ext_vector_type(4))) unsigned short ushort4v;
typedef __attribute__((ext_vector_type(2))) unsigned int uint2v;

static __device__ __forceinline__ unsigned short f2b(float f) {
  union { float f; unsigned int u; } v; v.f = f;
  unsigned int r = v.u + 0x7FFFu + ((v.u >> 16) & 1u);
  return (unsigned short)(r >> 16);
}

static __device__ __forceinline__ float exp2fast(float x) {
#if __has_builtin(__builtin_amdgcn_exp2f)
  return __builtin_amdgcn_exp2f(x);
#else
  return exp2f(x);
#endif
}

static __device__ __forceinline__ unsigned int cvtpk(float lo, float hi) {
  unsigned int r;
  asm("v_cvt_pk_bf16_f32 %0, %1, %2" : "=v"(r) : "v"(lo), "v"(hi));
  return r;
}

// Cross-lane ^16 / ^32 reduces via permlane*_swap (VALU path, ~2cy) instead of
// ds-shfl (~60cy). Verified correct in round 5 (passed absmax).
static __device__ __forceinline__ float xor16max(float x) {
#if __has_builtin(__builtin_amdgcn_permlane16_swap)
  unsigned u = __float_as_uint(x);
  uint2v r = __builtin_amdgcn_permlane16_swap(u, u, false, false);
  return fmaxf(__uint_as_float(r[0]), __uint_as_float(r[1]));
#else
  return fmaxf(x, __shfl_xor(x, 16));
#endif
}
static __device__ __forceinline__ float xor32max(float x) {
#if __has_builtin(__builtin_amdgcn_permlane32_swap)
  unsigned u = __float_as_uint(x);
  uint2v r = __builtin_amdgcn_permlane32_swap(u, u, false, false);
  return fmaxf(__uint_as_float(r[0]), __uint_as_float(r[1]));
#else
  return fmaxf(x, __shfl_xor(x, 32));
#endif
}
static __device__ __forceinline__ float xor16add(float x) {
#if __has_builtin(__builtin_amdgcn_permlane16_swap)
  unsigned u = __float_as_uint(x);
  uint2v r = __builtin_amdgcn_permlane16_swap(u, u, false, false);
  return __uint_as_float(r[0]) + __uint_as_float(r[1]);
#else
  return x + __shfl_xor(x, 16);
#endif
}
static __device__ __forceinline__ float xor32add(float x) {
#if __has_builtin(__builtin_amdgcn_permlane32_swap)
  unsigned u = __float_as_uint(x);
  uint2v r = __builtin_amdgcn_permlane32_swap(u, u, false, false);
  return __uint_as_float(r[0]) + __uint_as_float(r[1]);
#else
  return x + __shfl_xor(x, 32);
#endif
}

static __device__ __forceinline__ void gload16(const void* g, void* l) {
  __builtin_amdgcn_global_load_lds(
      (const __attribute__((address_space(1))) unsigned int*)g,
      (__attribute__((address_space(3))) unsigned int*)l, 16, 0, 0);
}

// ---------------- prep kernels ----------------

__global__ __launch_bounds__(256) void cast_x_kernel(const float* __restrict__ x,
                                                     unsigned short* __restrict__ xb) {
  int i = (blockIdx.x * 256 + threadIdx.x) * 4;
  float4 v = *(const float4*)(x + i);
  ushort4v o = { f2b(v.x), f2b(v.y), f2b(v.z), f2b(v.w) };
  *(ushort4v*)(xb + i) = o;
}

__global__ __launch_bounds__(256) void transpose_cast_kernel(
    const float* __restrict__ wq, const float* __restrict__ wk,
    const float* __restrict__ wv, const float* __restrict__ wo,
    unsigned short* __restrict__ wT) {
  const int z = blockIdx.z;
  const float* src = (z == 0) ? wq : (z == 1) ? wk : (z == 2) ? wv : wo;
  unsigned short* dst = wT + (size_t)z * 1048576;
  __shared__ float t[32][33];
  const int tid = threadIdx.x;
  const int tx = tid & 31, ty = tid >> 5;
  const int n0 = blockIdx.x * 32, k0 = blockIdx.y * 32;
#pragma unroll
  for (int i = 0; i < 4; ++i) {
    int r = ty + i * 8;
    t[r][tx] = src[(size_t)(k0 + r) * 1024 + n0 + tx];
  }
  __syncthreads();
#pragma unroll
  for (int i = 0; i < 4; ++i) {
    int r = ty + i * 8;
    dst[(size_t)(n0 + r) * 1024 + k0 + tx] = f2b(t[tx][r]);
  }
}

__global__ __launch_bounds__(256) void rope_tab_kernel(float* __restrict__ ct,
                                                       float* __restrict__ st) {
  int i = blockIdx.x * 256 + threadIdx.x;  // 2048*32 entries
  int s = i >> 5, p = i & 31;
  float ang = (float)s * powf(10000.0f, -(float)(2 * p) / 64.0f);
  ct[i] = cosf(ang);
  st[i] = sinf(ang);
}

// ---------------- GEMM (A: MxK row-major bf16, Bt: NxK row-major bf16) ----------------
// mode 0: Q epilogue (RoPE + fold 0.125*log2e, write (h,b,s,d)); mode 1: K epilogue;
// mode 2: V epilogue (write transposed (h,b,d,s)); mode 3: fp32 row-major out.

__global__ __launch_bounds__(256) void gemm_kernel(
    const unsigned short* __restrict__ A, const unsigned short* __restrict__ WT,
    unsigned short* __restrict__ Qb, unsigned short* __restrict__ Kb,
    unsigned short* __restrict__ VTb, float* __restrict__ Fout,
    const float* __restrict__ ctab, const float* __restrict__ stab, int finalMode) {
  __shared__ unsigned short As[128 * 32];
  __shared__ unsigned short Bs[128 * 32];
  const int tid = threadIdx.x;
  const int w = tid >> 6, lane = tid & 63;
  const int m0 = blockIdx.x * 128, n0 = blockIdx.y * 128;
  int mode;
  const unsigned short* Bt;
  if (finalMode) { mode = 3; Bt = WT; }
  else { mode = blockIdx.z; Bt = WT + (size_t)mode * 1048576; }
  const int wr = w >> 1, wc = w & 1;
  const int srow = lane >> 2, scol = lane & 3;
  f32x4 acc[4][4] = {};
  for (int k0 = 0; k0 < 1024; k0 += 32) {
#pragma unroll
    for (int c = 0; c < 2; ++c) {
      int chunk = w * 2 + c;
      gload16(A + (size_t)(m0 + chunk * 16 + srow) * 1024 + k0 + scol * 8,
              (char*)As + chunk * 1024);
      gload16(Bt + (size_t)(n0 + chunk * 16 + srow) * 1024 + k0 + scol * 8,
              (char*)Bs + chunk * 1024);
    }
    __syncthreads();
    short8 af[4], bf[4];
#pragma unroll
    for (int i = 0; i < 4; ++i) {
      af[i] = *(const short8*)((const char*)As +
              ((wr * 64 + i * 16 + (lane & 15)) * 64 + (lane >> 4) * 16));
      bf[i] = *(const short8*)((const char*)Bs +
              ((wc * 64 + i * 16 + (lane & 15)) * 64 + (lane >> 4) * 16));
    }
#pragma unroll
    for (int i = 0; i < 4; ++i)
#pragma unroll
      for (int j = 0; j < 4; ++j)
        acc[i][j] = __builtin_amdgcn_mfma_f32_16x16x32_bf16(af[i], bf[j], acc[i][j], 0, 0, 0);
    __syncthreads();
  }

  if (mode < 2) {
    unsigned short* dst = mode ? Kb : Qb;
    const float qscale = mode ? 1.0f : 0.125f * 1.44269504088896f;
#pragma unroll
    for (int i = 0; i < 4; ++i) {
#pragma unroll
      for (int j = 0; j < 4; ++j) {
        int n = n0 + wc * 64 + j * 16 + (lane & 15);
        int h = n >> 6, d = n & 63;
        int pairIdx = d >> 1;
        bool even = (n & 1) == 0;
#pragma unroll
        for (int r = 0; r < 4; ++r) {
          int m = m0 + wr * 64 + i * 16 + (lane >> 4) * 4 + r;
          int b = m >> 11, s = m & 2047;
          float v = acc[i][j][r];
          float pv = __shfl_xor(v, 1);
          float c = ctab[s * 32 + pairIdx], sn = stab[s * 32 + pairIdx];
          float ov = (even ? (v * c - pv * sn) : (pv * sn + v * c)) * qscale;
          dst[(size_t)((h * 2 + b) * 2048 + s) * 64 + d] = f2b(ov);
        }
      }
    }
  } else if (mode == 2) {
#pragma unroll
    for (int i = 0; i < 4; ++i) {
#pragma unroll
      for (int j = 0; j < 4; ++j) {
        int n = n0 + wc * 64 + j * 16 + (lane & 15);
        int h = n >> 6, d = n & 63;
        int mBase = m0 + wr * 64 + i * 16 + (lane >> 4) * 4;
        int b = mBase >> 11, s = mBase & 2047;
        ushort4v pk = { f2b(acc[i][j][0]), f2b(acc[i][j][1]),
                        f2b(acc[i][j][2]), f2b(acc[i][j][3]) };
        *(ushort4v*)(VTb + (size_t)((h * 2 + b) * 64 + d) * 2048 + s) = pk;
      }
    }
  } else {
#pragma unroll
    for (int i = 0; i < 4; ++i)
#pragma unroll
      for (int j = 0; j < 4; ++j) {
        int n = n0 + wc * 64 + j * 16 + (lane & 15);
#pragma unroll
        for (int r = 0; r < 4; ++r) {
          int m = m0 + wr * 64 + i * 16 + (lane >> 4) * 4 + r;
          Fout[(size_t)m * 1024 + n] = acc[i][j][r];
        }
      }
  }
}

// ---------------- causal flash attention ----------------
// Round-4 structure (separate H/L proc_tile: best occupancy/VGPR balance) +
// round-5's register-neutral chain cuts: permlane-swap reduces (VALU, not ds)
// and deferred l-sum (cross-lane reduce once in epilogue, not per tile).

__device__ __forceinline__ void proc_tile(
    const short8 aq[2], const unsigned short* Ksb, const unsigned short* Vsb,
    char* Psw, int lq, int lh, int wq16, bool diag,
    float& m, float& ls, f32x4* o) {
  const int swq = (lq & 7) << 4;
  f32x4 sacc[4] = {};
  __builtin_amdgcn_s_setprio(1);
#pragma unroll
  for (int ct = 0; ct < 4; ++ct) {
    const char* base = (const char*)Ksb + (ct * 16 + lq) * 128;
#pragma unroll
    for (int half = 0; half < 2; ++half) {
      short8 ak = *(const short8*)(base + ((half * 64 + lh * 16) ^ swq));
      sacc[ct] = __builtin_amdgcn_mfma_f32_16x16x32_bf16(ak, aq[half], sacc[ct], 0, 0, 0);
    }
  }
  __builtin_amdgcn_s_setprio(0);

  if (diag) {  // mask if k_local = 16ct + 4lh + r > q_local = wq16 + lq
    int rel = wq16 + lq - 4 * lh;
#pragma unroll
    for (int ct = 0; ct < 4; ++ct)
#pragma unroll
      for (int r = 0; r < 4; ++r)
        if (ct * 16 + r > rel) sacc[ct][r] = -__builtin_inff();
  }

  float mx0 = fmaxf(fmaxf(sacc[0][0], sacc[0][1]), fmaxf(sacc[0][2], sacc[0][3]));
  float mx1 = fmaxf(fmaxf(sacc[1][0], sacc[1][1]), fmaxf(sacc[1][2], sacc[1][3]));
  float mx2 = fmaxf(fmaxf(sacc[2][0], sacc[2][1]), fmaxf(sacc[2][2], sacc[2][3]));
  float mx3 = fmaxf(fmaxf(sacc[3][0], sacc[3][1]), fmaxf(sacc[3][2], sacc[3][3]));
  float mx = fmaxf(fmaxf(mx0, mx1), fmaxf(mx2, mx3));
  mx = xor16max(mx);
  mx = xor32max(mx);
  float nm = fmaxf(m, mx);
  float al = exp2fast(m - nm);
  m = nm;
  float ps = 0.f;
#pragma unroll
  for (int ct = 0; ct < 4; ++ct)
#pragma unroll
    for (int r = 0; r < 4; ++r) {
      float p = exp2fast(sacc[ct][r] - nm);
      sacc[ct][r] = p;
      ps += p;
    }
  ls = ls * al + ps;  // per-lane partial; cross-lane reduce deferred to epilogue
#pragma unroll
  for (int ct = 0; ct < 4; ++ct)
#pragma unroll
    for (int r = 0; r < 4; ++r) o[ct][r] *= al;

  // P[q=lq][k=16ct+4lh+{0..3}] -> one b64 write per ct (4 contiguous k)
#pragma unroll
  for (int ct = 0; ct < 4; ++ct) {
    uint2v pk = { cvtpk(sacc[ct][0], sacc[ct][1]), cvtpk(sacc[ct][2], sacc[ct][3]) };
    *(uint2v*)(Psw + lq * 128 + ((ct * 32 + lh * 8) ^ swq)) = pk;
  }
  __builtin_amdgcn_wave_barrier();
  short8 pa[2];
#pragma unroll
  for (int half = 0; half < 2; ++half)
    pa[half] = *(const short8*)(Psw + lq * 128 + ((half * 64 + lh * 16) ^ swq));

  __builtin_amdgcn_s_setprio(1);
#pragma unroll
  for (int ct = 0; ct < 4; ++ct) {
    const char* base = (const char*)Vsb + (ct * 16 + lq) * 128;
#pragma unroll
    for (int half = 0; half < 2; ++half) {
      short8 av = *(const short8*)(base + ((half * 64 + lh * 16) ^ swq));
      o[ct] = __builtin_amdgcn_mfma_f32_16x16x32_bf16(av, pa[half], o[ct], 0, 0, 0);
    }
  }
  __builtin_amdgcn_s_setprio(0);
}

__device__ __forceinline__ void store_o(
    const f32x4* o, float ls, char* Psw, unsigned short* __restrict__ Ob,
    int lane, int lq, int lh, int w, int qb, int h, int b) {
  float l = xor32add(xor16add(ls));  // deferred l reduction
  float invl = 1.0f / l;
#pragma unroll
  for (int ct = 0; ct < 4; ++ct)
#pragma unroll
    for (int r = 0; r < 4; ++r) {
      int d = ct * 16 + lh * 4 + r;
      *(unsigned short*)(Psw + lq * 128 + ((2 * d) ^ ((lq & 7) << 4))) =
          f2b(o[ct][r] * invl);
    }
  __builtin_amdgcn_wave_barrier();  // Psw is wave-private
#pragma unroll
  for (int pass = 0; pass < 2; ++pass) {
    int q2 = pass * 8 + (lane >> 3), d0 = (lane & 7) * 8;
    short8 vrow = *(const short8*)(Psw + q2 * 128 + ((2 * d0) ^ ((q2 & 7) << 4)));
    int s = qb + w * 16 + q2;
    *(short8*)(Ob + ((size_t)(b * 2048 + s)) * 1024 + h * 64 + d0) = vrow;
  }
  __builtin_amdgcn_wave_barrier();
}

__global__ __launch_bounds__(256) void attn_kernel(
    const unsigned short* __restrict__ Qb, const unsigned short* __restrict__ Kb,
    const unsigned short* __restrict__ VTb, unsigned short* __restrict__ Ob) {
  __shared__ unsigned short Ks[2][64 * 64];
  __shared__ unsigned short Vs[2][64 * 64];
  __shared__ unsigned short Ps[4 * 16 * 64];
  const int tid = threadIdx.x, w = tid >> 6, lane = tid & 63;
  const int qtL = blockIdx.x, qtH = 31 - blockIdx.x;
  const int hb = blockIdx.y;
  const int h = hb >> 1, b = hb & 1;
  const unsigned short* Qhb = Qb + (size_t)hb * 2048 * 64;
  const unsigned short* Khb = Kb + (size_t)hb * 2048 * 64;
  const unsigned short* Vhb = VTb + (size_t)hb * 64 * 2048;
  char* Psw = (char*)Ps + w * 2048;
  const int lq = lane & 15, lh = lane >> 4;
  const int wq16 = w * 16;

  short8 aqL[2], aqH[2];
  {
    int rowL = qtL * 64 + wq16 + lq;
    int rowH = qtH * 64 + wq16 + lq;
#pragma unroll
    for (int half = 0; half < 2; ++half) {
      aqL[half] = *(const short8*)(Qhb + (size_t)rowL * 64 + half * 32 + lh * 8);
      aqH[half] = *(const short8*)(Qhb + (size_t)rowH * 64 + half * 32 + lh * 8);
    }
  }
  float mL = -__builtin_inff(), lsL = 0.f;
  float mH = -__builtin_inff(), lsH = 0.f;
  f32x4 oL[4] = {}, oH[4] = {};

  // staging: thread owns rows r0, r0+32 (16B each)
  const int r0 = tid >> 3, f0 = tid & 7;
  const int so0 = r0 * 128 + ((f0 * 16) ^ ((r0 & 7) << 4));
  short8 gK[2], gV[2];
  gK[0] = *(const short8*)(Khb + (size_t)r0 * 64 + f0 * 8);
  gK[1] = *(const short8*)(Khb + (size_t)(r0 + 32) * 64 + f0 * 8);
  gV[0] = *(const short8*)(Vhb + (size_t)r0 * 2048 + f0 * 8);
  gV[1] = *(const short8*)(Vhb + (size_t)(r0 + 32) * 2048 + f0 * 8);
  *(short8*)((char*)Ks[0] + so0) = gK[0];
  *(short8*)((char*)Ks[0] + so0 + 32 * 128) = gK[1];
  *(short8*)((char*)Vs[0] + so0) = gV[0];
  *(short8*)((char*)Vs[0] + so0 + 32 * 128) = gV[1];
  __syncthreads();

  for (int kt = 0; kt <= qtH; ++kt) {
    const int cur = kt & 1;
    if (kt < qtH) {  // issue next tile's loads; latency hides under compute
      int kk0 = (kt + 1) * 64;
      gK[0] = *(const short8*)(Khb + (size_t)(kk0 + r0) * 64 + f0 * 8);
      gK[1] = *(const short8*)(Khb + (size_t)(kk0 + r0 + 32) * 64 + f0 * 8);
      gV[0] = *(const short8*)(Vhb + (size_t)r0 * 2048 + kk0 + f0 * 8);
      gV[1] = *(const short8*)(Vhb + (size_t)(r0 + 32) * 2048 + kk0 + f0 * 8);
    }
    proc_tile(aqH, Ks[cur], Vs[cur], Psw, lq, lh, wq16, kt == qtH, mH, lsH, oH);
    if (kt <= qtL)
      proc_tile(aqL, Ks[cur], Vs[cur], Psw, lq, lh, wq16, kt == qtL, mL, lsL, oL);
    if (kt < qtH) {  // write next tile into the other buffer
      *(short8*)((char*)Ks[cur ^ 1] + so0) = gK[0];
      *(short8*)((char*)Ks[cur ^ 1] + so0 + 32 * 128) = gK[1];
      *(short8*)((char*)Vs[cur ^ 1] + so0) = gV[0];
      *(short8*)((char*)Vs[cur ^ 1] + so0 + 32 * 128) = gV[1];
    }
    __syncthreads();
  }

  store_o(oL, lsL, Psw, Ob, lane, lq, lh, w, qtL * 64, h, b);
  store_o(oH, lsH, Psw, Ob, lane, lq, lh, w, qtH * 64, h, b);
}

// ---------------- launch ----------------

extern "C" void kernel_launch(void* const* d_in, const int* in_sizes, int n_in,
                              void* d_out, int out_size, void* d_ws, size_t ws_size,
                              hipStream_t stream) {
  const float* x  = (const float*)d_in[0];
  const float* wq = (const float*)d_in[1];
  const float* wk = (const float*)d_in[2];
  const float* wv = (const float*)d_in[3];
  const float* wo = (const float*)d_in[4];
  float* out = (float*)d_out;

  char* ws = (char*)d_ws;
  const size_t SZ = 8388608;  // 8 MiB
  unsigned short* xb  = (unsigned short*)(ws);
  unsigned short* wT  = (unsigned short*)(ws + SZ);       // 4 x 2MiB (q,k,v,o)
  unsigned short* Qb  = (unsigned short*)(ws + 2 * SZ);
  unsigned short* Kb  = (unsigned short*)(ws + 3 * SZ);
  unsigned short* VTb = (unsigned short*)(ws + 4 * SZ);
  unsigned short* Ob  = (unsigned short*)(ws + 5 * SZ);
  float* ctab = (float*)(ws + 6 * SZ);
  float* stab = (float*)(ws + 6 * SZ + 262144);
  if (ws_size < 6 * SZ + 2 * 262144) return;  // ws too small: fail loudly (zeros)

  cast_x_kernel<<<4096, 256, 0, stream>>>(x, xb);
  transpose_cast_kernel<<<dim3(32, 32, 4), 256, 0, stream>>>(wq, wk, wv, wo, wT);
  rope_tab_kernel<<<256, 256, 0, stream>>>(ctab, stab);
  gemm_kernel<<<dim3(32, 8, 3), 256, 0, stream>>>(xb, wT, Qb, Kb, VTb, nullptr, ctab, stab, 0);
  attn_kernel<<<dim3(16, 32), 256, 0, stream>>>(Qb, Kb, VTb, Ob);
  gemm_kernel<<<dim3(32, 8, 1), 256, 0, stream>>>(Ob, wT + 3 * 1048576, Qb, Kb, VTb, out,
                                                  ctab, stab, 1);
}